// Round 7
// baseline (373.103 us; speedup 1.0000x reference)
//
#include <hip/hip_runtime.h>

// Problem constants
#define BB 2048
#define TT 3
#define VV 62
#define FF 5
#define HH 64

// Output layout (flat, return order): x_residual[2048*62*64], Sloss, dloss, S[2048*62*62]
#define XR_OFF 0
#define SL_OFF 8126464
#define DL_OFF 8126465
#define S_OFF  8126466

#define ALPHA_F 1e-4f
#define INV_SQRT310 0.05679618342470648f  // 1/sqrt(62*5)
#define INV_SQRT15  0.2581988897471611f   // 1/sqrt(3*5)

typedef float f32x2 __attribute__((ext_vector_type(2)));

// compiler-ordering fence for wave-synchronous LDS phases (no code emitted)
#define WFENCE() do { __builtin_amdgcn_wave_barrier(); __asm__ __volatile__("" ::: "memory"); } while (0)

// Prep: transpose tw (o,c,t) -> twt (t,c,o) in workspace, zero the two loss accumulators.
__global__ void prep_kernel(const float* __restrict__ tw, float* __restrict__ twt,
                            float* __restrict__ out) {
    int i = blockIdx.x * 256 + threadIdx.x;
    if (i < 12288) {
        int t = i >> 12, r = i & 4095, c = r >> 6, o = r & 63;
        twt[i] = tw[o * 192 + c * 3 + t];
    }
    if (i < 2) out[SL_OFF + i] = 0.f;
}

__launch_bounds__(256, 2)
__global__ void stgcn_kernel(
    const float* __restrict__ x,     const float* __restrict__ U1,
    const float* __restrict__ U2,    const float* __restrict__ U3,
    const float* __restrict__ be,    const float* __restrict__ Ve,
    const float* __restrict__ W1,    const float* __restrict__ W2,
    const float* __restrict__ W3,    const float* __restrict__ bs,
    const float* __restrict__ Vs,    const float* __restrict__ a,
    const float* __restrict__ Theta, const float* __restrict__ twt,
    const float* __restrict__ tb,    const float* __restrict__ rw,
    const float* __restrict__ rb,    const float* __restrict__ gamma_,
    const float* __restrict__ beta_, float* __restrict__ out)
{
    // LDS: 930+3844+3844+1132+3968+3968 = 17686 floats = 70744 B (2 blocks/CU)
    __shared__ float sx[930];    // x[b] [t][v][f]          (alive whole kernel)
    __shared__ float sS[3844];   // tmpS (from P1) -> C1n = -S*At
    __shared__ float sAt[3844];  // Sm(raw) -> C2=(2S^2-I)*At
    __shared__ float sU[1132];   // union scratch
    __shared__ float sP[3968];   // sig; stage F gcn swizzled; z
    __shared__ float sVs[3968];  // Vs padded [62][64] for ds_read_b128

    // stage B/C view of sU
    float* const sL    = sU;          // 186  temporal lhs -> s_lhs [v][3]
    float* const sR    = sU + 186;    // 186  temporal rhs [v][t3]
    float* const sR0   = sU + 372;    // 186  R0[t][v] = sum_f W3[f]*x[t][v][f]
    float* const sRr   = sU + 558;    // 186  s_rhs [t][v62]
    float* const sy    = sU + 744;    // 15
    float* const sprod = sU + 759;    // 9
    float* const sE    = sU + 768;    // 9
    float* const stA   = sU + 777;    // 9
    // softmax-stats view (B/C buffers dead by Sm time)
    float* const sMq   = sU;          // 4*64 per-wave col max
    float* const sSq   = sU + 256;    // 4*64 per-wave col expsum
    float* const sM    = sU + 512;    // 62   final col max
    float* const sInv  = sU + 576;    // 62   1/den
    // stage D/F view
    float* const sG    = sU;          // 992  G_t [v][16]
    float* const sDiag = sU + 992;    // 62   diag of spatial_At
    float* const scol  = sU + 1054;   // 62   1/colsum of tmpS (written in P1!)
    float* const sred  = sU + 1116;   // 16   reductions

    const int b   = blockIdx.x;
    const int tid = threadIdx.x;
    const int o   = tid & 63;
    const int q   = tid >> 6;
    const int qu  = __builtin_amdgcn_readfirstlane(q);
    const int nv  = (qu < 2) ? 16 : 15;                    // #valid rows u = qu + 4r

    // ---- stage A: loads (x + padded Vs) ----
    for (int i = tid; i < 930; i += 256) sx[i] = x[b * 930 + i];
    for (int i = tid; i < 3844; i += 256) {
        int u = i / 62, w = i - u * 62;
        sVs[u * 64 + w] = Vs[i];
    }
    __syncthreads();

    // ==== P1: wave 0 runs the whole temporal-attention chain wave-synchronously;
    //          waves 1-3 concurrently compute tmpS + colsum + dloss ====
    if (q == 0) {
        // a) temporal rhs[v][t], R0[t][v] (lane<62); y[t][f] (lanes 0-14)
        if (o < 62) {
            #pragma unroll
            for (int t = 0; t < 3; ++t) {
                float s = 0.f, s0 = 0.f;
                #pragma unroll
                for (int f = 0; f < 5; ++f) {
                    float xv = sx[t * 310 + o * 5 + f];
                    s  += U3[f] * xv;
                    s0 += W3[f] * xv;
                }
                sR[o * 3 + t]   = s;
                sR0[t * 62 + o] = s0;
            }
        }
        if (o < 15) {
            int t = o / 5, f = o % 5;
            float s = 0.f;
            for (int v = 0; v < 62; ++v) s += sx[t * 310 + v * 5 + f] * U1[v];
            sy[o] = s;
        }
        WFENCE();
        // b) lhs[t][u] (lane<62 handles u=o for all t)
        if (o < 62) {
            #pragma unroll
            for (int t = 0; t < 3; ++t) {
                float s = 0.f;
                #pragma unroll
                for (int f = 0; f < 5; ++f) s += sy[t * 5 + f] * U2[f * 62 + o];
                sL[t * 62 + o] = s;
            }
        }
        WFENCE();
        // c) prod[t][u] (9 lanes)
        if (o < 9) {
            int t = o / 3, u = o - t * 3;
            float s = 0.f;
            for (int v = 0; v < 62; ++v) s += sL[t * 62 + v] * sR[v * 3 + u];
            sprod[o] = s;
        }
        WFENCE();
        // d) E[t][u] (9 lanes)
        if (o < 9) {
            int t = o / 3, u = o - t * 3;
            float s = 0.f;
            #pragma unroll
            for (int ss = 0; ss < 3; ++ss) {
                float p = sprod[ss * 3 + u] + be[ss * 3 + u];
                s += Ve[t * 3 + ss] * (1.f / (1.f + __expf(-p)));
            }
            sE[o] = s;
        }
        WFENCE();
        // e) temporal softmax (3 lanes) -> stA
        if (o < 3) {
            int u = o;
            float m = fmaxf(fmaxf(sE[u], sE[3 + u]), sE[6 + u]);
            float e0 = __expf(sE[u] - m);
            float e1 = __expf(sE[3 + u] - m);
            float e2 = __expf(sE[6 + u] - m);
            float inv = 1.f / (e0 + e1 + e2);
            stA[u]     = e0 * inv;
            stA[3 + u] = e1 * inv;
            stA[6 + u] = e2 * inv;
        }
    } else {
        // tmpS columns (wave w: 21/21/20 cols), colsum via shuffle; dloss on wave 3
        float a5[5];
        #pragma unroll
        for (int f = 0; f < 5; ++f) a5[f] = a[f];
        float xi[5];
        #pragma unroll
        for (int f = 0; f < 5; ++f) xi[f] = (o < 62) ? sx[310 + o * 5 + f] : 0.f;
        const int j0 = (qu - 1) * 21;
        const int jc = (qu < 3) ? 21 : 20;
        for (int jj = 0; jj < jc; ++jj) {
            int j = j0 + jj;
            float s = 0.f;
            #pragma unroll
            for (int f = 0; f < 5; ++f) s += fabsf(xi[f] - sx[310 + j * 5 + f]) * a5[f];
            float e = (o < 62) ? __expf(fmaxf(s, 0.f)) : 0.f;
            if (o < 62) sS[o * 62 + j] = e;
            float cs = e;
            #pragma unroll
            for (int m = 1; m < 64; m <<= 1) cs += __shfl_xor(cs, m, 64);
            if (o == 0) scol[j] = 1.f / cs;
        }
        if (qu == 3) {
            #pragma unroll
            for (int f = 0; f < 5; ++f) {
                float su = xi[f], sq2 = xi[f] * xi[f];
                #pragma unroll
                for (int m = 1; m < 64; m <<= 1) {
                    su  += __shfl_xor(su, m, 64);
                    sq2 += __shfl_xor(sq2, m, 64);
                }
                if (o == 0) sred[8 + f] = 124.f * sq2 - 2.f * su * su;
            }
        }
    }
    __syncthreads();

    // ---- stage C: s_lhs / s_rhs (x_TAt factored out) ----
    if (tid < 186) {
        float w1t[3];
        #pragma unroll
        for (int t = 0; t < 3; ++t) {
            float s = 0.f;
            #pragma unroll
            for (int u = 0; u < 3; ++u) s += W1[u] * stA[t * 3 + u];
            w1t[t] = s;
        }
        int v = tid / 3, s3 = tid - v * 3;
        float s = 0.f;
        #pragma unroll
        for (int f = 0; f < 5; ++f) {
            float z = 0.f;
            #pragma unroll
            for (int t = 0; t < 3; ++t) z += sx[t * 310 + v * 5 + f] * w1t[t];
            s += z * W2[f * 3 + s3];
        }
        sL[v * 3 + s3] = s * INV_SQRT310;
        int u2 = tid / 62, v2 = tid - u2 * 62;
        float s2 = 0.f;
        #pragma unroll
        for (int t = 0; t < 3; ++t) s2 += stA[t * 3 + u2] * sR0[t * 62 + v2];
        sRr[u2 * 62 + v2] = s2 * INV_SQRT310;
    }
    __syncthreads();
    // sig[u][v] -> sP (sS holds tmpS)
    for (int i = tid; i < 3844; i += 256) {
        int u = i / 62, v = i - u * 62;
        float s = bs[i];
        #pragma unroll
        for (int t = 0; t < 3; ++t) s += sL[u * 3 + t] * sRr[t * 62 + v];
        sP[i] = 1.f / (1.f + __expf(-s));
    }
    __syncthreads();

    // ---- Sm: register-blocked (cs[8] reused over 16 rows), Vs via ds_read_b128
    //      broadcast; online softmax col-stats folded in ----
    if (o < 62) {
        float accr[16];
        #pragma unroll
        for (int r = 0; r < 16; ++r) accr[r] = 0.f;
        #pragma unroll 1
        for (int wc = 0; wc < 56; wc += 8) {
            float cs[8];
            #pragma unroll
            for (int k = 0; k < 8; ++k) cs[k] = sP[(wc + k) * 62 + o];
            #pragma unroll
            for (int r = 0; r < 16; ++r) {
                if (r < nv) {
                    const float4* vr4 = reinterpret_cast<const float4*>(sVs + (qu + 4 * r) * 64 + wc);
                    float4 v0 = vr4[0], v1 = vr4[1];
                    accr[r] += v0.x * cs[0] + v0.y * cs[1] + v0.z * cs[2] + v0.w * cs[3]
                             + v1.x * cs[4] + v1.y * cs[5] + v1.z * cs[6] + v1.w * cs[7];
                }
            }
        }
        {   // tail: w = 56..61
            float cs[6];
            #pragma unroll
            for (int k = 0; k < 6; ++k) cs[k] = sP[(56 + k) * 62 + o];
            #pragma unroll
            for (int r = 0; r < 16; ++r) {
                if (r < nv) {
                    const float4* vr4 = reinterpret_cast<const float4*>(sVs + (qu + 4 * r) * 64 + 56);
                    float4 v0 = vr4[0];
                    const f32x2* vr2 = reinterpret_cast<const f32x2*>(sVs + (qu + 4 * r) * 64 + 60);
                    f32x2 v1 = vr2[0];
                    accr[r] += v0.x * cs[0] + v0.y * cs[1] + v0.z * cs[2] + v0.w * cs[3]
                             + v1.x * cs[4] + v1.y * cs[5];
                }
            }
        }
        // write raw Sm rows + online column stats for this wave's rows
        float m = -1e30f, ssum = 0.f;
        #pragma unroll
        for (int r = 0; r < 16; ++r) {
            if (r < nv) {
                float val = accr[r];
                sAt[(qu + 4 * r) * 62 + o] = val;
                float mn = fmaxf(m, val);
                ssum = ssum * __expf(m - mn) + __expf(val - mn);
                m = mn;
            }
        }
        sMq[qu * 64 + o] = m;
        sSq[qu * 64 + o] = ssum;
    }
    __syncthreads();
    // combine per-column stats
    if (tid < 62) {
        int v = tid;
        float m0 = sMq[v], m1 = sMq[64 + v], m2 = sMq[128 + v], m3 = sMq[192 + v];
        float M = fmaxf(fmaxf(m0, m1), fmaxf(m2, m3));
        float den = sSq[v] * __expf(m0 - M) + sSq[64 + v] * __expf(m1 - M)
                  + sSq[128 + v] * __expf(m2 - M) + sSq[192 + v] * __expf(m3 - M);
        sM[v]   = M;
        sInv[v] = 1.f / den;
    }
    __syncthreads();

    // ---- phase 4: normalize S, fused softmax-At, C1n/C2, Sloss ----
    float slp = 0.f;
    for (int idx = tid; idx < 3844; idx += 256) {
        int i = idx / 62, j = idx - i * 62;
        float sv = sS[idx] * scol[j];
        out[S_OFF + (size_t)b * 3844 + idx] = sv;
        slp += sv * sv;
        float A = __expf(sAt[idx] - sM[j]) * sInv[j];    // softmaxed At on the fly
        if (i == j) sDiag[i] = A;
        sS[idx] = -sv * A;                               // C1 PRE-NEGATED
        float c2 = 2.f * sv * sv; if (i == j) c2 -= 1.f;
        sAt[idx] = c2 * A;                               // C2 = (2S^2 - I)*At
    }
    for (int m = 32; m > 0; m >>= 1) slp += __shfl_down(slp, m, 64);
    if ((tid & 63) == 0) sred[q] = slp;
    __syncthreads();
    if (tid == 0) {
        atomicAdd(out + SL_OFF, (sred[0] + sred[1] + sred[2] + sred[3]) * (ALPHA_F / 2048.f));
        float dl = sred[8] + sred[9] + sred[10] + sred[11] + sred[12];
        atomicAdd(out + DL_OFF, dl * ALPHA_F);
    }

    // ---- stage F: spatial GCN + temporal conv (R5 proven scalar forms) ----
    float th[15];                                          // Theta[kf][o] in regs
    #pragma unroll
    for (int kf = 0; kf < 15; ++kf) th[kf] = Theta[kf * 64 + o];

    const int vlane = o;           // step3/z-phase lane role: v
    const int qo    = qu * 16;     // this wave's o-chunk
    const int swz   = vlane & 31;

    float acc[16];
    #pragma unroll
    for (int m = 0; m < 16; ++m) acc[m] = 0.f;

    for (int t = 0; t < 3; ++t) {
        __syncthreads();
        // step1: pk over {C1n, C2}
        for (int i = tid; i < 310; i += 256) {
            int v = i / 5, f = i - v * 5;
            float g0 = sDiag[v] * sx[t * 310 + i];
            f32x2 g12 = {0.f, 0.f};
            for (int u = 0; u < 62; ++u) {
                float xa = sx[t * 310 + u * 5 + f];
                f32x2 cc; cc.x = sS[u * 62 + v]; cc.y = sAt[u * 62 + v];
                g12 += cc * (f32x2){xa, xa};
            }
            sG[v * 16 + f]      = g0;
            sG[v * 16 + 5 + f]  = g12.x;   // C1 pre-negated -> already -S·x
            sG[v * 16 + 10 + f] = g12.y;
        }
        __syncthreads();
        // step2: lane o computes gcn[v][o] via 4x ds_read_b128; write XOR-swizzled sP
        #pragma unroll 2
        for (int j = 0; j < 16; ++j) {
            if (j < nv) {
                int v = qu + 4 * j;
                const float4* g4 = reinterpret_cast<const float4*>(sG + v * 16);
                float4 a0 = g4[0], a1 = g4[1], a2 = g4[2], a3 = g4[3];
                float s = a0.x*th[0]  + a0.y*th[1]  + a0.z*th[2]  + a0.w*th[3]
                        + a1.x*th[4]  + a1.y*th[5]  + a1.z*th[6]  + a1.w*th[7]
                        + a2.x*th[8]  + a2.y*th[9]  + a2.z*th[10] + a2.w*th[11]
                        + a3.x*th[12] + a3.y*th[13] + a3.z*th[14];
                sP[v * 64 + (o ^ (v & 31))] = fmaxf(s, 0.f);
            }
        }
        __syncthreads();
        // step3: lane=v; per c: 1 LDS read + 4 wave-uniform float4 twt loads + 16 fma
        const float* twtp = twt + t * 4096;
        #pragma unroll 2
        for (int c = 0; c < 64; ++c) {
            float g = sP[vlane * 64 + (c ^ swz)];
            const float4* wr = reinterpret_cast<const float4*>(twtp + c * 64 + qo);
            float4 w0 = wr[0], w1 = wr[1], w2 = wr[2], w3 = wr[3];
            acc[0]  += g * w0.x;  acc[1]  += g * w0.y;
            acc[2]  += g * w0.z;  acc[3]  += g * w0.w;
            acc[4]  += g * w1.x;  acc[5]  += g * w1.y;
            acc[6]  += g * w1.z;  acc[7]  += g * w1.w;
            acc[8]  += g * w2.x;  acc[9]  += g * w2.y;
            acc[10] += g * w2.z;  acc[11] += g * w2.w;
            acc[12] += g * w3.x;  acc[13] += g * w3.y;
            acc[14] += g * w3.z;  acc[15] += g * w3.w;
        }
    }

    // ---- z-phase: lane=v computes z[v][qo+m], stage in sP ----
    __syncthreads();
    if (vlane < 62) {
        float x5[5];
        #pragma unroll
        for (int f = 0; f < 5; ++f) x5[f] = sx[vlane * 5 + f];   // x[:,0]
        #pragma unroll
        for (int m = 0; m < 16; ++m) {
            int oo = qo + m;
            float r = rb[oo];
            #pragma unroll
            for (int f = 0; f < 5; ++f) r += x5[f] * rw[oo * 5 + f];
            float z = r + (acc[m] + tb[oo]) * INV_SQRT15;
            sP[vlane * 64 + (oo ^ swz)] = fmaxf(z, 0.f);
        }
    }
    __syncthreads();

    // ---- epilogue: lane=o, LayerNorm over o ----
    const float gam = gamma_[o], bet = beta_[o];
    #pragma unroll
    for (int j = 0; j < 16; ++j) {
        if (j < nv) {
            int v = qu + 4 * j;
            float z = sP[v * 64 + (o ^ (v & 31))];
            float s1 = z, s2 = z * z;
            #pragma unroll
            for (int m = 1; m < 64; m <<= 1) {
                s1 += __shfl_xor(s1, m, 64);
                s2 += __shfl_xor(s2, m, 64);
            }
            float mean = s1 * 0.015625f;
            float var  = s2 * 0.015625f - mean * mean;
            float ov   = (z - mean) * rsqrtf(var + 1e-5f) * gam + bet;
            out[XR_OFF + (size_t)b * 3968 + v * 64 + o] = ov;
        }
    }
}

extern "C" void kernel_launch(void* const* d_in, const int* in_sizes, int n_in,
                              void* d_out, int out_size, void* d_ws, size_t ws_size,
                              hipStream_t stream) {
    const float* x   = (const float*)d_in[0];
    const float* U1  = (const float*)d_in[1];
    const float* U2  = (const float*)d_in[2];
    const float* U3  = (const float*)d_in[3];
    const float* be  = (const float*)d_in[4];
    const float* Ve  = (const float*)d_in[5];
    const float* W1  = (const float*)d_in[6];
    const float* W2  = (const float*)d_in[7];
    const float* W3  = (const float*)d_in[8];
    const float* bs  = (const float*)d_in[9];
    const float* Vs  = (const float*)d_in[10];
    const float* a   = (const float*)d_in[11];
    const float* Th  = (const float*)d_in[12];
    const float* tw  = (const float*)d_in[13];
    const float* tb  = (const float*)d_in[14];
    const float* rw  = (const float*)d_in[15];
    const float* rb  = (const float*)d_in[16];
    const float* gm  = (const float*)d_in[17];
    const float* bt  = (const float*)d_in[18];
    float* out = (float*)d_out;
    float* twt = (float*)d_ws;  // 12288 floats

    prep_kernel<<<48, 256, 0, stream>>>(tw, twt, out);
    stgcn_kernel<<<2048, 256, 0, stream>>>(x, U1, U2, U3, be, Ve, W1, W2, W3,
                                           bs, Vs, a, Th, twt, tb, rw, rb, gm, bt, out);
}

// Round 8
// 294.865 us; speedup vs baseline: 1.2653x; 1.2653x over previous
//
#include <hip/hip_runtime.h>

// Problem constants
#define BB 2048
#define TT 3
#define VV 62
#define FF 5
#define HH 64

// Output layout (flat, return order): x_residual[2048*62*64], Sloss, dloss, S[2048*62*62]
#define XR_OFF 0
#define SL_OFF 8126464
#define DL_OFF 8126465
#define S_OFF  8126466

#define ALPHA_F 1e-4f
#define INV_SQRT310 0.05679618342470648f  // 1/sqrt(62*5)
#define INV_SQRT15  0.2581988897471611f   // 1/sqrt(3*5)

typedef float f32x2 __attribute__((ext_vector_type(2)));
typedef float f32x4 __attribute__((ext_vector_type(4)));
typedef _Float16 f16x8 __attribute__((ext_vector_type(8)));

// Prep: repack tw (o,c,t) into f16 MFMA B-fragment layout in workspace:
//   wh[ ((t*4+ot)*2+kk)*512 + l*8 + j ] = tw[o=ot*16+(l&15)][c=kk*32+(l>>4)*8+j][t]
// Lane l's 8 contiguous f16 = one dwordx4 B-fragment load. Also zero loss accumulators.
__global__ void prep_kernel(const float* __restrict__ tw, _Float16* __restrict__ wh,
                            float* __restrict__ out) {
    int i = blockIdx.x * 256 + threadIdx.x;
    if (i < 12288) {
        int t  = i / 4096, r2 = i - t * 4096;
        int ot = r2 >> 10, r3 = r2 & 1023;
        int kk = r3 >> 9,  r4 = r3 & 511;
        int l  = r4 >> 3,  j  = r4 & 7;
        int o  = ot * 16 + (l & 15);
        int c  = kk * 32 + ((l >> 4) << 3) + j;
        wh[i] = (_Float16)tw[o * 192 + c * 3 + t];
    }
    if (i < 2) out[SL_OFF + i] = 0.f;
}

__launch_bounds__(256, 2)
__global__ void stgcn_kernel(
    const float* __restrict__ x,     const float* __restrict__ U1,
    const float* __restrict__ U2,    const float* __restrict__ U3,
    const float* __restrict__ be,    const float* __restrict__ Ve,
    const float* __restrict__ W1,    const float* __restrict__ W2,
    const float* __restrict__ W3,    const float* __restrict__ bs,
    const float* __restrict__ Vs,    const float* __restrict__ a,
    const float* __restrict__ Theta, const _Float16* __restrict__ Wh,
    const float* __restrict__ tb,    const float* __restrict__ rw,
    const float* __restrict__ rb,    const float* __restrict__ gamma_,
    const float* __restrict__ beta_, float* __restrict__ out)
{
    // LDS: 13718 floats (54872 B) + sPh 4096 f16 (8192 B) = 63064 B  (2 blocks/CU)
    __shared__ float sx[930];    // x[b] [t][v][f]           (alive whole kernel)
    __shared__ float sS[3844];   // sig -> tmpS -> C1n = -S*At
    __shared__ float sAt[3844];  // Sm(raw) -> C2=(2S^2-I)*At
    __shared__ float sU[1132];   // union scratch
    __shared__ float sP[3968];   // softmax/colsum partials; tc fragments; z
    __shared__ _Float16 sPh[4096]; // gcn[v][c] f16, XOR-swizzled, MFMA A-operand

    // stage B/C view of sU
    float* const sL    = sU;          // 186
    float* const sR    = sU + 186;    // 186
    float* const sR0   = sU + 372;    // 186
    float* const sRr   = sU + 558;    // 186
    float* const sy    = sU + 744;    // 15
    float* const sprod = sU + 759;    // 9
    float* const sE    = sU + 768;    // 9
    float* const stA   = sU + 777;    // 9
    // stage D/F view of sU
    float* const sG    = sU;          // 992  G_t [v][16]
    float* const sDiag = sU + 992;    // 62
    float* const scol  = sU + 1054;   // 62
    float* const sred  = sU + 1116;   // 16

    const int b   = blockIdx.x;
    const int tid = threadIdx.x;
    const int o   = tid & 63;
    const int q   = tid >> 6;
    const int qu  = __builtin_amdgcn_readfirstlane(q);
    const int nv  = (qu < 2) ? 16 : 15;                    // #valid v = qu + 4j

    // ---- stage A: loads ----
    for (int i = tid; i < 930; i += 256) sx[i] = x[b * 930 + i];
    __syncthreads();

    // ---- stage B: temporal attention ----
    if (tid < 15) {
        int t = tid / 5, f = tid % 5;
        float s = 0.f;
        for (int v = 0; v < 62; ++v) s += sx[t * 310 + v * 5 + f] * U1[v];
        sy[tid] = s;
    }
    if (tid < 186) {
        int v = tid / 3, t = tid % 3;
        float s = 0.f, s0 = 0.f;
        #pragma unroll
        for (int f = 0; f < 5; ++f) {
            float xv = sx[t * 310 + v * 5 + f];
            s  += U3[f] * xv;
            s0 += W3[f] * xv;
        }
        sR[v * 3 + t]  = s;
        sR0[t * 62 + v] = s0;
    }
    __syncthreads();
    if (tid < 186) {
        int t = tid / 62, u = tid % 62;
        float s = 0.f;
        for (int f = 0; f < 5; ++f) s += sy[t * 5 + f] * U2[f * 62 + u];
        sL[t * 62 + u] = s;
    }
    __syncthreads();
    if (tid < 9) {
        int t = tid / 3, u = tid - (tid / 3) * 3;
        float s = 0.f;
        for (int v = 0; v < 62; ++v) s += sL[t * 62 + v] * sR[v * 3 + u];
        sprod[tid] = s;
    }
    __syncthreads();
    if (tid < 9) {
        int t = tid / 3, u = tid - (tid / 3) * 3;
        float s = 0.f;
        for (int ss = 0; ss < 3; ++ss) {
            float p  = sprod[ss * 3 + u] + be[ss * 3 + u];
            float sg = 1.f / (1.f + __expf(-p));
            s += Ve[t * 3 + ss] * sg;
        }
        sE[tid] = s;
    }
    __syncthreads();
    if (tid < 3) {
        int u = tid;
        float m = -1e30f;
        for (int t = 0; t < 3; ++t) m = fmaxf(m, sE[t * 3 + u]);
        float e0 = __expf(sE[0 * 3 + u] - m);
        float e1 = __expf(sE[1 * 3 + u] - m);
        float e2 = __expf(sE[2 * 3 + u] - m);
        float inv = 1.f / (e0 + e1 + e2);
        stA[0 * 3 + u] = e0 * inv;
        stA[1 * 3 + u] = e1 * inv;
        stA[2 * 3 + u] = e2 * inv;
    }
    __syncthreads();

    // ---- stage C: spatial attention (x_TAt factored out) ----
    if (tid < 186) {
        float w1t[3];
        #pragma unroll
        for (int t = 0; t < 3; ++t) {
            float s = 0.f;
            #pragma unroll
            for (int u = 0; u < 3; ++u) s += W1[u] * stA[t * 3 + u];
            w1t[t] = s;
        }
        int v = tid / 3, s3 = tid - v * 3;
        float s = 0.f;
        #pragma unroll
        for (int f = 0; f < 5; ++f) {
            float z = 0.f;
            #pragma unroll
            for (int t = 0; t < 3; ++t) z += sx[t * 310 + v * 5 + f] * w1t[t];
            s += z * W2[f * 3 + s3];
        }
        sL[v * 3 + s3] = s * INV_SQRT310;
        int u2 = tid / 62, v2 = tid - u2 * 62;
        float s2 = 0.f;
        #pragma unroll
        for (int t = 0; t < 3; ++t) s2 += stA[t * 3 + u2] * sR0[t * 62 + v2];
        sRr[u2 * 62 + v2] = s2 * INV_SQRT310;
    }
    __syncthreads();
    // sig[u][v] -> sS
    for (int i = tid; i < 3844; i += 256) {
        int u = i / 62, v = i - u * 62;
        float s = bs[i];
        for (int t = 0; t < 3; ++t) s += sL[u * 3 + t] * sRr[t * 62 + v];
        sS[i] = 1.f / (1.f + __expf(-s));
    }
    __syncthreads();
    // Sm[u][v] = sum_w Vs[u][w]*sig[w][v]  — pk-packed over w pairs; u wave-uniform
    if (o < 62) {
        for (int r = 0; r < nv; ++r) {
            int u = qu + 4 * r;
            const float* vr = Vs + u * 62;
            f32x2 s2 = {0.f, 0.f};
            for (int w = 0; w < 62; w += 2) {
                f32x2 vv; vv.x = vr[w];            vv.y = vr[w + 1];
                f32x2 ss; ss.x = sS[w * 62 + o];   ss.y = sS[(w + 1) * 62 + o];
                s2 += vv * ss;
            }
            sAt[u * 62 + o] = s2.x + s2.y;   // RAW Sm (softmax deferred)
        }
    }
    __syncthreads();

    // ---- phase 2: tmpS (column-mapped, colsum free) + softmax col-stats + dloss ----
    {
        int j = o;
        if (j < 62) {
            int i0 = qu * 16, i1 = (qu == 3) ? 62 : i0 + 16;
            float mq = -1e30f;
            for (int u = i0; u < i1; ++u) mq = fmaxf(mq, sAt[u * 62 + j]);
            float sq = 0.f;
            for (int u = i0; u < i1; ++u) sq += __expf(sAt[u * 62 + j] - mq);
            sP[qu * 64 + j]       = mq;
            sP[256 + qu * 64 + j] = sq;
            float xj[5];
            #pragma unroll
            for (int f = 0; f < 5; ++f) xj[f] = sx[310 + j * 5 + f];
            float cp = 0.f;
            for (int i = i0; i < i1; ++i) {
                float s = 0.f;
                #pragma unroll
                for (int f = 0; f < 5; ++f)
                    s += fabsf(sx[310 + i * 5 + f] - xj[f]) * a[f];
                float e = __expf(fmaxf(s, 0.f));
                sS[i * 62 + j] = e;
                cp += e;
            }
            sP[512 + qu * 64 + j] = cp;
        } else {
            int f = (o == 62) ? qu : (qu == 0 ? 4 : -1);
            if (f >= 0) {
                float su = 0.f, sq2 = 0.f;
                for (int v = 0; v < 62; ++v) {
                    float xv = sx[310 + v * 5 + f];
                    su += xv; sq2 += xv * xv;
                }
                sred[8 + f] = 124.f * sq2 - 2.f * su * su;
            }
        }
    }
    __syncthreads();
    // ---- phase 3: per-column combines ----
    if (tid < 62) {
        int v = tid;
        float m0 = sP[v], m1 = sP[64 + v], m2 = sP[128 + v], m3 = sP[192 + v];
        float M = fmaxf(fmaxf(m0, m1), fmaxf(m2, m3));
        float den = sP[256 + v] * __expf(m0 - M) + sP[320 + v] * __expf(m1 - M)
                  + sP[384 + v] * __expf(m2 - M) + sP[448 + v] * __expf(m3 - M);
        sP[768 + v] = M;
        sP[832 + v] = 1.f / den;
        scol[v] = 1.f / (sP[512 + v] + sP[576 + v] + sP[640 + v] + sP[704 + v]);
    }
    __syncthreads();
    // ---- phase 4: normalize S, fused softmax-At, C1n/C2, Sloss ----
    float slp = 0.f;
    for (int idx = tid; idx < 3844; idx += 256) {
        int i = idx / 62, j = idx - i * 62;
        float sv = sS[idx] * scol[j];
        out[S_OFF + (size_t)b * 3844 + idx] = sv;
        slp += sv * sv;
        float A = __expf(sAt[idx] - sP[768 + j]) * sP[832 + j];
        if (i == j) sDiag[i] = A;
        sS[idx] = -sv * A;                              // C1 PRE-NEGATED
        float c2 = 2.f * sv * sv; if (i == j) c2 -= 1.f;
        sAt[idx] = c2 * A;                              // C2 = (2S^2 - I)*At
    }
    for (int m = 32; m > 0; m >>= 1) slp += __shfl_down(slp, m, 64);
    if ((tid & 63) == 0) sred[q] = slp;
    __syncthreads();
    if (tid == 0) {
        atomicAdd(out + SL_OFF, (sred[0] + sred[1] + sred[2] + sred[3]) * (ALPHA_F / 2048.f));
        float dl = sred[8] + sred[9] + sred[10] + sred[11] + sred[12];
        atomicAdd(out + DL_OFF, dl * ALPHA_F);
    }

    // ---- stage F: spatial GCN (VALU) + temporal conv (MFMA) ----
    float th[15];
    #pragma unroll
    for (int kf = 0; kf < 15; ++kf) th[kf] = Theta[kf * 64 + o];

    const int lane  = o;
    const int vlane = o;           // z-phase lane role
    const int qo    = qu * 16;
    const int swz   = vlane & 31;

    // zero sPh padding rows 62,63 (A-operand tail of M-tile 3)
    if (tid < 128) sPh[62 * 64 + tid] = (_Float16)0.f;

    f32x4 acc[4];                  // acc[ot]: D-tile (M=qu*16.., N=ot*16..), accumulated over kk,t
    #pragma unroll
    for (int ot = 0; ot < 4; ++ot) acc[ot] = (f32x4){0.f, 0.f, 0.f, 0.f};

    const f16x8* Wp = (const f16x8*)Wh;

    for (int t = 0; t < 3; ++t) {
        __syncthreads();
        // step1: G_t[v][kf], pk over {C1n, C2}
        for (int i = tid; i < 310; i += 256) {
            int v = i / 5, f = i - v * 5;
            float g0 = sDiag[v] * sx[t * 310 + i];
            f32x2 g12 = {0.f, 0.f};
            for (int u = 0; u < 62; ++u) {
                float xa = sx[t * 310 + u * 5 + f];
                f32x2 cc; cc.x = sS[u * 62 + v]; cc.y = sAt[u * 62 + v];
                g12 += cc * (f32x2){xa, xa};
            }
            sG[v * 16 + f]      = g0;
            sG[v * 16 + 5 + f]  = g12.x;
            sG[v * 16 + 10 + f] = g12.y;
        }
        __syncthreads();
        // step2: gcn[v][c=o] = relu(G·Theta) -> f16, XOR-swizzled sPh[v][c ^ ((v&7)<<3)]
        #pragma unroll 2
        for (int j = 0; j < 16; ++j) {
            if (j < nv) {
                int v = qu + 4 * j;
                const float4* g4 = reinterpret_cast<const float4*>(sG + v * 16);
                float4 a0 = g4[0], a1 = g4[1], a2 = g4[2], a3 = g4[3];
                float s = a0.x*th[0]  + a0.y*th[1]  + a0.z*th[2]  + a0.w*th[3]
                        + a1.x*th[4]  + a1.y*th[5]  + a1.z*th[6]  + a1.w*th[7]
                        + a2.x*th[8]  + a2.y*th[9]  + a2.z*th[10] + a2.w*th[11]
                        + a3.x*th[12] + a3.y*th[13] + a3.z*th[14];
                sPh[v * 64 + (o ^ ((v & 7) << 3))] = (_Float16)fmaxf(s, 0.f);
            }
        }
        __syncthreads();
        // step3: MFMA. Wave qu owns M-tile qu (rows qu*16..+15). K=64 = 2 kk-blocks.
        {
            int r0 = qu * 16 + (lane & 15);
            int cb = (lane >> 4) << 3;                 // k-offset of this lane's 8 elements
            int sw = (r0 & 7) << 3;
            f16x8 A0 = *(const f16x8*)(sPh + r0 * 64 + ((cb) ^ sw));        // kk=0
            f16x8 A1 = *(const f16x8*)(sPh + r0 * 64 + ((32 + cb) ^ sw));   // kk=1
            #pragma unroll
            for (int ot = 0; ot < 4; ++ot) {
                f16x8 B0 = Wp[((t * 4 + ot) * 2 + 0) * 64 + lane];
                f16x8 B1 = Wp[((t * 4 + ot) * 2 + 1) * 64 + lane];
                acc[ot] = __builtin_amdgcn_mfma_f32_16x16x32_f16(A0, B0, acc[ot], 0, 0, 0);
                acc[ot] = __builtin_amdgcn_mfma_f32_16x16x32_f16(A1, B1, acc[ot], 0, 0, 0);
            }
        }
    }

    // ---- fragment store: tc (C/D layout: col=lane&15, row=(lane>>4)*4+reg) -> sP swizzled ----
    #pragma unroll
    for (int ot = 0; ot < 4; ++ot) {
        #pragma unroll
        for (int rg = 0; rg < 4; ++rg) {
            int v = qu * 16 + ((lane >> 4) << 2) + rg;
            if (v < 62) {
                int oo = ot * 16 + (lane & 15);
                sP[v * 64 + (oo ^ (v & 31))] = acc[ot][rg];
            }
        }
    }
    __syncthreads();

    // ---- z-phase: lane=v reads tc from sP, adds res, writes z back ----
    if (vlane < 62) {
        float x5[5];
        #pragma unroll
        for (int f = 0; f < 5; ++f) x5[f] = sx[vlane * 5 + f];   // x[:,0]
        #pragma unroll
        for (int m = 0; m < 16; ++m) {
            int oo = qo + m;
            float tcv = sP[vlane * 64 + (oo ^ swz)];
            float r = rb[oo];
            #pragma unroll
            for (int f = 0; f < 5; ++f) r += x5[f] * rw[oo * 5 + f];
            float z = r + (tcv + tb[oo]) * INV_SQRT15;
            sP[vlane * 64 + (oo ^ swz)] = fmaxf(z, 0.f);
        }
    }
    __syncthreads();

    // ---- epilogue: lane=o, LayerNorm over o ----
    const float gam = gamma_[o], bet = beta_[o];
    #pragma unroll
    for (int j = 0; j < 16; ++j) {
        if (j < nv) {
            int v = qu + 4 * j;
            float z = sP[v * 64 + (o ^ (v & 31))];
            float s1 = z, s2 = z * z;
            #pragma unroll
            for (int m = 1; m < 64; m <<= 1) {
                s1 += __shfl_xor(s1, m, 64);
                s2 += __shfl_xor(s2, m, 64);
            }
            float mean = s1 * 0.015625f;
            float var  = s2 * 0.015625f - mean * mean;
            float ov   = (z - mean) * rsqrtf(var + 1e-5f) * gam + bet;
            out[XR_OFF + (size_t)b * 3968 + v * 64 + o] = ov;
        }
    }
}

extern "C" void kernel_launch(void* const* d_in, const int* in_sizes, int n_in,
                              void* d_out, int out_size, void* d_ws, size_t ws_size,
                              hipStream_t stream) {
    const float* x   = (const float*)d_in[0];
    const float* U1  = (const float*)d_in[1];
    const float* U2  = (const float*)d_in[2];
    const float* U3  = (const float*)d_in[3];
    const float* be  = (const float*)d_in[4];
    const float* Ve  = (const float*)d_in[5];
    const float* W1  = (const float*)d_in[6];
    const float* W2  = (const float*)d_in[7];
    const float* W3  = (const float*)d_in[8];
    const float* bs  = (const float*)d_in[9];
    const float* Vs  = (const float*)d_in[10];
    const float* a   = (const float*)d_in[11];
    const float* Th  = (const float*)d_in[12];
    const float* tw  = (const float*)d_in[13];
    const float* tb  = (const float*)d_in[14];
    const float* rw  = (const float*)d_in[15];
    const float* rb  = (const float*)d_in[16];
    const float* gm  = (const float*)d_in[17];
    const float* bt  = (const float*)d_in[18];
    float* out = (float*)d_out;
    _Float16* wh = (_Float16*)d_ws;  // 12288 f16 = 24576 B

    prep_kernel<<<48, 256, 0, stream>>>(tw, wh, out);
    stgcn_kernel<<<2048, 256, 0, stream>>>(x, U1, U2, U3, be, Ve, W1, W2, W3,
                                           bs, Vs, a, Th, wh, tb, rw, rb, gm, bt, out);
}